// Round 16
// baseline (510.748 us; speedup 1.0000x reference)
//
#include <hip/hip_runtime.h>

#define NCP    64
#define BTS    16
#define NTPL   2048
#define TSTEPS 6
#define DTF    0.2f                      // 1/(T-1)
#define L2E    1.4426950408889634f       // log2(e)

// ---------- fast scalar helpers ----------
__device__ __forceinline__ float fast_rcp(float x) { return __builtin_amdgcn_rcpf(x); }
__device__ __forceinline__ float fexp2(float x)    { return __builtin_amdgcn_exp2f(x); }
__device__ __forceinline__ float fast_tanh(float x) {        // shoot path
    float e = __expf(2.0f * x);
    return 1.0f - 2.0f * fast_rcp(1.0f + e);
}

// ======================================================================
// Single symmetrized 2x2 kernel block (plain sigmoid — R11-proven).
// Local w layout: [0..39]=W1t [40..49]=b1t [50..149]=W2t
//                 [150..159]=C0 [160..169]=C1 [170..179]=C2
// Global wt layout: W1t[0..39] b1t[40..49] W2t[50..149] b2t[150..159]
//                   C0[160..169] C1[170..179] C2[180..189] b3t[190..192]
// ======================================================================
__device__ __forceinline__ void kblock(
    float x0, float x1, float p0, float p1,
    const float (&w)[180], const float* __restrict__ wt,
    float& M00, float& M01, float& M11)
{
    float ra[10], rb[10];
#pragma unroll
    for (int k = 0; k < 10; ++k) {
        float ta = fmaf(p1, w[30 + k],
                   fmaf(p0, w[20 + k],
                   fmaf(x1, w[10 + k],
                   fmaf(x0, w[k], w[40 + k]))));
        float tb = fmaf(x1, w[30 + k],
                   fmaf(x0, w[20 + k],
                   fmaf(p1, w[10 + k],
                   fmaf(p0, w[k], w[40 + k]))));
        ra[k] = fast_rcp(1.0f + fexp2(ta));
        rb[k] = fast_rcp(1.0f + fexp2(tb));
    }
    float ua[10], ub[10];
#pragma unroll
    for (int k = 0; k < 10; ++k) {
        float bb = wt[150 + k];
        ua[k] = fmaf(ra[0], w[50 + k], bb);
        ub[k] = fmaf(rb[0], w[50 + k], bb);
    }
#pragma unroll
    for (int c = 1; c < 10; ++c) {
#pragma unroll
        for (int k = 0; k < 10; ++k) {
            float ww = w[50 + c * 10 + k];
            ua[k] = fmaf(ra[c], ww, ua[k]);
            ub[k] = fmaf(rb[c], ww, ub[k]);
        }
    }
    float Oa = wt[190], Ob = wt[190];
    float T1a = wt[191], T1b = wt[191];
    float T2a = wt[192], T2b = wt[192];
#pragma unroll
    for (int c = 0; c < 10; ++c) {
        float r2a = fast_rcp(1.0f + fexp2(ua[c]));
        float r2b = fast_rcp(1.0f + fexp2(ub[c]));
        Oa  = fmaf(r2a, w[150 + c], Oa);   Ob  = fmaf(r2b, w[150 + c], Ob);
        T1a = fmaf(r2a, w[160 + c], T1a);  T1b = fmaf(r2b, w[160 + c], T1b);
        T2a = fmaf(r2a, w[170 + c], T2a);  T2b = fmaf(r2b, w[170 + c], T2b);
    }
    M00 = fexp2(T1a) + fexp2(T1b);
    M01 = Oa + Ob;
    M11 = fexp2(T2a) + fexp2(T2b);
}

// ======================================================================
// Quad kernel block (R15-proven): 4 template points, 8 MLP streams.
// ======================================================================
__device__ __forceinline__ void kblock4(
    const float (&x0)[4], const float (&x1)[4], float p0, float p1,
    const float (&w)[180], const float* __restrict__ wt,
    float (&M00)[4], float (&M01)[4], float (&M11)[4])
{
    float r[8][10];
#pragma unroll
    for (int k = 0; k < 10; ++k) {
        float w0 = w[k], w1 = w[10 + k], w2 = w[20 + k], w3 = w[30 + k];
        float bb = w[40 + k];
#pragma unroll
        for (int m = 0; m < 4; ++m) {
            float ta = fmaf(p1, w3, fmaf(p0, w2,
                       fmaf(x1[m], w1, fmaf(x0[m], w0, bb))));
            float tb = fmaf(x1[m], w3, fmaf(x0[m], w2,
                       fmaf(p1, w1, fmaf(p0, w0, bb))));
            r[2 * m][k]     = fast_rcp(1.0f + fexp2(ta));
            r[2 * m + 1][k] = fast_rcp(1.0f + fexp2(tb));
        }
    }
    float u[8][10];
#pragma unroll
    for (int k = 0; k < 10; ++k) {
        float bb = wt[150 + k];
        float ww = w[50 + k];
#pragma unroll
        for (int s = 0; s < 8; ++s) u[s][k] = fmaf(r[s][0], ww, bb);
    }
#pragma unroll
    for (int c = 1; c < 10; ++c) {
#pragma unroll
        for (int k = 0; k < 10; ++k) {
            float ww = w[50 + c * 10 + k];
#pragma unroll
            for (int s = 0; s < 8; ++s) u[s][k] = fmaf(r[s][c], ww, u[s][k]);
        }
    }
    float O[8], A[8], B[8];
#pragma unroll
    for (int s = 0; s < 8; ++s) { O[s] = wt[190]; A[s] = wt[191]; B[s] = wt[192]; }
#pragma unroll
    for (int c = 0; c < 10; ++c) {
        float c0 = w[150 + c], c1 = w[160 + c], c2 = w[170 + c];
#pragma unroll
        for (int s = 0; s < 8; ++s) {
            float g = fast_rcp(1.0f + fexp2(u[s][c]));
            O[s] = fmaf(g, c0, O[s]);
            A[s] = fmaf(g, c1, A[s]);
            B[s] = fmaf(g, c2, B[s]);
        }
    }
#pragma unroll
    for (int m = 0; m < 4; ++m) {
        M00[m] = fexp2(A[2 * m]) + fexp2(A[2 * m + 1]);
        M01[m] = O[2 * m] + O[2 * m + 1];
        M11[m] = fexp2(B[2 * m]) + fexp2(B[2 * m + 1]);
    }
}

// Load the 180 hot weights: 3 lane-strided vector loads + __shfl distribute.
__device__ __forceinline__ void load_w(const float* __restrict__ wt,
                                       int lane, float (&w)[180])
{
    float c0 = wt[lane];            // wt[0..63]
    float c1 = wt[64 + lane];       // wt[64..127]
    float c2 = wt[128 + lane];      // wt[128..191]
#pragma unroll
    for (int t = 0; t < 180; ++t) {
        int src = (t < 150) ? t : (t + 10);   // skip b2t at wt[150..159]
        int ch = src >> 6, ix = src & 63;
        float v = (ch == 0) ? c0 : (ch == 1) ? c1 : c2;
        w[t] = __shfl(v, ix);
    }
}

// ======================================================================
// FUSED shooting: 16 batch blocks x 512 threads (8 waves) + 1 transform
// block. Wave wv handles a = sub*8+wv (8 a's); lane = b. Batch state in
// LDS, __syncthreads between the 6 steps. launch_bounds(512,2): 2
// waves/SIMD -> 256-VGPR budget (R4's 1024-thr version got 64 and
// spilled; that was the failure, not the structure).
// ======================================================================
__global__ __launch_bounds__(512, 2)
void shoot_all(const float* __restrict__ q0, const float* __restrict__ cp,
               const float* __restrict__ W1, const float* __restrict__ b1,
               const float* __restrict__ W2, const float* __restrict__ b2,
               const float* __restrict__ W3, const float* __restrict__ b3,
               float* __restrict__ p_hist, float* __restrict__ q_hist,
               float* __restrict__ wt)
{
    if (blockIdx.x == BTS) {
        // ---- weight transform for the flow kernels ----
        int t = threadIdx.x;
        if (t < 40) wt[t] = 2.0f * L2E * W1[t];
        if (t < 10) wt[40 + t] = 2.0f * L2E * b1[t];
        if (t < 100) wt[50 + t] = -4.0f * L2E * W2[t];
        if (t < 10) {
            float s = b2[t];
            for (int c = 0; c < 10; ++c) s += W2[c * 10 + t];
            wt[150 + t] = 2.0f * L2E * s;                 // b2''
            wt[160 + t] = -W3[t * 3 + 0];                 // C0 (0.5 * -2)
            wt[170 + t] = -2.0f * L2E * W3[t * 3 + 1];    // C1
            wt[180 + t] = -2.0f * L2E * W3[t * 3 + 2];    // C2
        }
        if (t < 3) {
            float s = b3[t];
            for (int c = 0; c < 10; ++c) s += W3[c * 3 + t];
            wt[190 + t] = (t == 0) ? 0.5f * s : fmaf(L2E, s, -1.0f);
        }
        return;
    }

    int batch = blockIdx.x;
    int wv = threadIdx.x >> 6;      // 0..7
    int b  = threadIdx.x & 63;

    __shared__ float P[NCP][2], Q[NCP][2];
    if (threadIdx.x < NCP) {
        int t = threadIdx.x;
        P[t][0] = cp[2 * t];
        P[t][1] = cp[2 * t + 1];
        Q[t][0] = q0[(batch * NCP + t) * 2 + 0];
        Q[t][1] = q0[(batch * NCP + t) * 2 + 1];
    }
    __syncthreads();

    for (int s = 0; s < TSTEPS; ++s) {
        float np[8][2], nq[8][2];

#pragma unroll
        for (int sub = 0; sub < 8; ++sub) {
            int a = (sub << 3) | wv;
            float pax = P[a][0], pay = P[a][1];
            float qax = Q[a][0], qay = Q[a][1];
            float pbx = P[b][0], pby = P[b][1];
            float qbx = Q[b][0], qby = Q[b][1];

            float dhq_x = 0.f, dhq_y = 0.f;
            float g_x = 0.f, g_y = 0.f;
            float cross = fmaf(qax, qby, qay * qbx);

#pragma unroll
            for (int e = 0; e < 2; ++e) {
                float z0 = e ? pbx : pax;
                float z1 = e ? pby : pay;
                float z2 = e ? pax : pbx;
                float z3 = e ? pay : pby;

                float h1[10];
#pragma unroll
                for (int k = 0; k < 10; ++k) {
                    float u = fmaf(z3, W1[30 + k],
                              fmaf(z2, W1[20 + k],
                              fmaf(z1, W1[10 + k],
                              fmaf(z0, W1[k], b1[k]))));
                    h1[k] = fast_tanh(u);
                }
                float u2[10];
#pragma unroll
                for (int k = 0; k < 10; ++k) u2[k] = b2[k];
#pragma unroll
                for (int c = 0; c < 10; ++c) {
#pragma unroll
                    for (int k = 0; k < 10; ++k) u2[k] = fmaf(h1[c], W2[c * 10 + k], u2[k]);
                }
                float h2[10];
                float o0 = b3[0], o1 = b3[1], o2 = b3[2];
#pragma unroll
                for (int c = 0; c < 10; ++c) {
                    h2[c] = fast_tanh(u2[c]);
                    o0 = fmaf(h2[c], W3[c * 3 + 0], o0);
                    o1 = fmaf(h2[c], W3[c * 3 + 1], o1);
                    o2 = fmaf(h2[c], W3[c * 3 + 2], o2);
                }
                float e1 = __expf(o1), e2 = __expf(o2);

                dhq_x = fmaf(0.5f, fmaf(e1, qbx, o0 * qby), dhq_x);
                dhq_y = fmaf(0.5f, fmaf(o0, qbx, e2 * qby), dhq_y);

                float d0 = cross;
                float d1 = e1 * qax * qbx;
                float d2 = e2 * qay * qby;

                float du2[10];
#pragma unroll
                for (int c = 0; c < 10; ++c) {
                    float dh2 = fmaf(W3[c * 3 + 0], d0,
                                fmaf(W3[c * 3 + 1], d1, W3[c * 3 + 2] * d2));
                    du2[c] = dh2 * (1.0f - h2[c] * h2[c]);
                }
                float du1[10];
#pragma unroll
                for (int c = 0; c < 10; ++c) {
                    float dh1 = 0.f;
#pragma unroll
                    for (int k = 0; k < 10; ++k) dh1 = fmaf(W2[c * 10 + k], du2[k], dh1);
                    du1[c] = dh1 * (1.0f - h1[c] * h1[c]);
                }
                int c0 = e ? 2 : 0;
                float ga = 0.f, gb = 0.f;
#pragma unroll
                for (int k = 0; k < 10; ++k) {
                    ga = fmaf(W1[(0 + c0) * 10 + k], du1[k], ga);
                    gb = fmaf(W1[(1 + c0) * 10 + k], du1[k], gb);
                }
                g_x = fmaf(0.5f, ga, g_x);
                g_y = fmaf(0.5f, gb, g_y);
            }

#pragma unroll
            for (int off = 32; off > 0; off >>= 1) {
                dhq_x += __shfl_xor(dhq_x, off);
                dhq_y += __shfl_xor(dhq_y, off);
                g_x   += __shfl_xor(g_x, off);
                g_y   += __shfl_xor(g_y, off);
            }
            np[sub][0] = fmaf(DTF, dhq_x, pax);
            np[sub][1] = fmaf(DTF, dhq_y, pay);
            nq[sub][0] = fmaf(-DTF, g_x, qax);
            nq[sub][1] = fmaf(-DTF, g_y, qay);
        }

        __syncthreads();   // all LDS reads done before update
        if (b == 0) {
#pragma unroll
            for (int sub = 0; sub < 8; ++sub) {
                int a = (sub << 3) | wv;
                P[a][0] = np[sub][0]; P[a][1] = np[sub][1];
                Q[a][0] = nq[sub][0]; Q[a][1] = nq[sub][1];
                size_t o = (((size_t)(s + 1) * BTS + batch) * NCP + a) * 2;
                p_hist[o] = np[sub][0]; p_hist[o + 1] = np[sub][1];
                q_hist[o] = nq[sub][0]; q_hist[o + 1] = nq[sub][1];
            }
        }
        __syncthreads();
    }
}

// ======================================================================
// Flow step 0: x == tpl, p == cp for ALL batches -> one kblock per (i,j),
// apply all 16 batches' q. Writes x^(1) into d_out.
// ======================================================================
__global__ __launch_bounds__(256, 1)
void flow_step0(const float* __restrict__ tpl, const float* __restrict__ cp,
                const float* __restrict__ q0, float* __restrict__ out,
                const float* __restrict__ wt)
{
    int i = blockIdx.x * 4 + (threadIdx.x >> 6);
    int j = threadIdx.x & 63;

    float w[180];
    load_w(wt, j, w);

    float x0 = tpl[2 * i], x1 = tpl[2 * i + 1];
    float p0 = cp[2 * j],  p1 = cp[2 * j + 1];

    float M00, M01, M11;
    kblock(x0, x1, p0, p1, w, wt, M00, M01, M11);

    const float2* __restrict__ q = (const float2*)q0;
#pragma unroll
    for (int bt = 0; bt < BTS; ++bt) {
        float2 qq = q[bt * NCP + j];
        float vx = fmaf(M00, qq.x, M01 * qq.y);
        float vy = fmaf(M01, qq.x, M11 * qq.y);
#pragma unroll
        for (int off = 32; off > 0; off >>= 1) {
            vx += __shfl_xor(vx, off);
            vy += __shfl_xor(vy, off);
        }
        if (j == 0) {
            out[((size_t)bt * NTPL + i) * 2 + 0] = fmaf(DTF, vx, x0);
            out[((size_t)bt * NTPL + i) * 2 + 1] = fmaf(DTF, vy, x1);
        }
    }
}

// ======================================================================
// Flow steps 1..6: wave = (batch, 4 template points); lane = cp j.
// kblock4: 8 interleaved MLP streams per lane. (R15-proven, 204 us.)
// ======================================================================
__global__ __launch_bounds__(256, 1)
void flow_rest(const float* __restrict__ p_hist, const float* __restrict__ q_hist,
               float* __restrict__ out, const float* __restrict__ wt)
{
    int wid = blockIdx.x * 4 + (threadIdx.x >> 6);   // 0..BTS*NTPL/4-1
    int j = threadIdx.x & 63;
    int u0 = wid * 4;
    int batch = u0 >> 11;
    int i0 = u0 & (NTPL - 1);                        // i0..i0+3, same batch

    float w[180];
    load_w(wt, j, w);

    const float2* __restrict__ ph = (const float2*)p_hist;
    const float2* __restrict__ qh = (const float2*)q_hist;

    size_t ob = ((size_t)batch * NTPL + i0) * 2;
    float x0[4], x1[4];
#pragma unroll
    for (int m = 0; m < 4; ++m) {
        x0[m] = out[ob + 2 * m];
        x1[m] = out[ob + 2 * m + 1];
    }

#pragma unroll
    for (int s = 0; s < TSTEPS; ++s) {
        int idx = ((s + 1) * BTS + batch) * NCP + j;
        float2 P = ph[idx];
        float2 Q = qh[idx];
        float M00[4], M01[4], M11[4];
        kblock4(x0, x1, P.x, P.y, w, wt, M00, M01, M11);
        float vx[4], vy[4];
#pragma unroll
        for (int m = 0; m < 4; ++m) {
            vx[m] = fmaf(M00[m], Q.x, M01[m] * Q.y);
            vy[m] = fmaf(M01[m], Q.x, M11[m] * Q.y);
        }
#pragma unroll
        for (int off = 32; off > 0; off >>= 1) {
#pragma unroll
            for (int m = 0; m < 4; ++m) {
                vx[m] += __shfl_xor(vx[m], off);
                vy[m] += __shfl_xor(vy[m], off);
            }
        }
#pragma unroll
        for (int m = 0; m < 4; ++m) {
            x0[m] = fmaf(DTF, vx[m], x0[m]);
            x1[m] = fmaf(DTF, vy[m], x1[m]);
        }
    }

    if (j == 0) {
#pragma unroll
        for (int m = 0; m < 4; ++m) {
            out[ob + 2 * m]     = x0[m];
            out[ob + 2 * m + 1] = x1[m];
        }
    }
}

extern "C" void kernel_launch(void* const* d_in, const int* in_sizes, int n_in,
                              void* d_out, int out_size, void* d_ws, size_t ws_size,
                              hipStream_t stream)
{
    const float* q0  = (const float*)d_in[0];   // [16,64,2]
    const float* tpl = (const float*)d_in[1];   // [2048,2]
    const float* cp  = (const float*)d_in[2];   // [64,2]
    const float* W1  = (const float*)d_in[3];   // [4,10]
    const float* b1  = (const float*)d_in[4];   // [10]
    const float* W2  = (const float*)d_in[5];   // [10,10]
    const float* b2  = (const float*)d_in[6];   // [10]
    const float* W3  = (const float*)d_in[7];   // [10,3]
    const float* b3  = (const float*)d_in[8];   // [3]
    float* out = (float*)d_out;

    float* ws = (float*)d_ws;
    const int slab = BTS * NCP * 2;                      // 2048 floats / slice
    float* p_hist = ws;                                  // 7 slabs (slot 0 unused)
    float* q_hist = ws + (size_t)7 * slab;
    float* wt     = ws + (size_t)14 * slab;              // 193 floats

    shoot_all<<<BTS + 1, 512, 0, stream>>>(q0, cp, W1, b1, W2, b2, W3, b3,
                                           p_hist, q_hist, wt);
    flow_step0<<<NTPL / 4, 256, 0, stream>>>(tpl, cp, q0, out, wt);
    flow_rest<<<BTS * NTPL / 16, 256, 0, stream>>>(p_hist, q_hist, out, wt);
}

// Round 17
// 298.966 us; speedup vs baseline: 1.7084x; 1.7084x over previous
//
#include <hip/hip_runtime.h>

#define NCP    64
#define BTS    16
#define NTPL   2048
#define TSTEPS 6
#define DTF    0.2f                      // 1/(T-1)
#define L2E    1.4426950408889634f       // log2(e)

// ---------- fast scalar helpers ----------
__device__ __forceinline__ float fast_rcp(float x) { return __builtin_amdgcn_rcpf(x); }
__device__ __forceinline__ float fexp2(float x)    { return __builtin_amdgcn_exp2f(x); }
__device__ __forceinline__ float fast_tanh(float x) {        // shoot path
    float e = __expf(2.0f * x);
    return 1.0f - 2.0f * fast_rcp(1.0f + e);
}

// ======================================================================
// Raw-weight shfl load (shoot + self-transforming flow_step0):
// w[0..39]=W1 raw, [40..49]=b1, [50..149]=W2 raw, [150..179]=W3 raw.
// VGPR-resident via __shfl so no per-iteration s_load churn (R11 lesson).
// ======================================================================
__device__ __forceinline__ void load_raw_w(
    const float* __restrict__ W1, const float* __restrict__ b1,
    const float* __restrict__ W2, const float* __restrict__ W3,
    int lane, float (&w)[180])
{
    float cA = (lane < 40) ? W1[lane] : (lane < 50 ? b1[lane - 40] : 0.f);
    float cB0 = W2[lane];
    float cB1 = (lane < 36) ? W2[64 + lane] : 0.f;
    float cC  = (lane < 30) ? W3[lane] : 0.f;
#pragma unroll
    for (int t = 0; t < 50; ++t)  w[t] = __shfl(cA, t);
#pragma unroll
    for (int t = 0; t < 64; ++t)  w[50 + t] = __shfl(cB0, t);
#pragma unroll
    for (int t = 0; t < 36; ++t)  w[114 + t] = __shfl(cB1, t);
#pragma unroll
    for (int t = 0; t < 30; ++t)  w[150 + t] = __shfl(cC, t);
}

// Transformed-weight shfl load for flow_rest (wt written by transform blk).
// Local w: [0..39]=W1t [40..49]=b1t [50..149]=W2t [150..159]=C0
//          [160..169]=C1 [170..179]=C2
__device__ __forceinline__ void load_w(const float* __restrict__ wt,
                                       int lane, float (&w)[180])
{
    float c0 = wt[lane];
    float c1 = wt[64 + lane];
    float c2 = wt[128 + lane];
#pragma unroll
    for (int t = 0; t < 180; ++t) {
        int src = (t < 150) ? t : (t + 10);   // skip b2t at wt[150..159]
        int ch = src >> 6, ix = src & 63;
        float v = (ch == 0) ? c0 : (ch == 1) ? c1 : c2;
        w[t] = __shfl(v, ix);
    }
}

// ======================================================================
// Quad kernel block (R15-proven): 4 template points, 8 MLP streams.
// Transformed weights. REQUIRES 256-VGPR budget (launch_bounds(256,1)).
// ======================================================================
__device__ __forceinline__ void kblock4(
    const float (&x0)[4], const float (&x1)[4], float p0, float p1,
    const float (&w)[180], const float* __restrict__ wt,
    float (&M00)[4], float (&M01)[4], float (&M11)[4])
{
    float r[8][10];
#pragma unroll
    for (int k = 0; k < 10; ++k) {
        float w0 = w[k], w1 = w[10 + k], w2 = w[20 + k], w3 = w[30 + k];
        float bb = w[40 + k];
#pragma unroll
        for (int m = 0; m < 4; ++m) {
            float ta = fmaf(p1, w3, fmaf(p0, w2,
                       fmaf(x1[m], w1, fmaf(x0[m], w0, bb))));
            float tb = fmaf(x1[m], w3, fmaf(x0[m], w2,
                       fmaf(p1, w1, fmaf(p0, w0, bb))));
            r[2 * m][k]     = fast_rcp(1.0f + fexp2(ta));
            r[2 * m + 1][k] = fast_rcp(1.0f + fexp2(tb));
        }
    }
    float u[8][10];
#pragma unroll
    for (int k = 0; k < 10; ++k) {
        float bb = wt[150 + k];
        float ww = w[50 + k];
#pragma unroll
        for (int s = 0; s < 8; ++s) u[s][k] = fmaf(r[s][0], ww, bb);
    }
#pragma unroll
    for (int c = 1; c < 10; ++c) {
#pragma unroll
        for (int k = 0; k < 10; ++k) {
            float ww = w[50 + c * 10 + k];
#pragma unroll
            for (int s = 0; s < 8; ++s) u[s][k] = fmaf(r[s][c], ww, u[s][k]);
        }
    }
    float O[8], A[8], B[8];
#pragma unroll
    for (int s = 0; s < 8; ++s) { O[s] = wt[190]; A[s] = wt[191]; B[s] = wt[192]; }
#pragma unroll
    for (int c = 0; c < 10; ++c) {
        float c0 = w[150 + c], c1 = w[160 + c], c2 = w[170 + c];
#pragma unroll
        for (int s = 0; s < 8; ++s) {
            float g = fast_rcp(1.0f + fexp2(u[s][c]));
            O[s] = fmaf(g, c0, O[s]);
            A[s] = fmaf(g, c1, A[s]);
            B[s] = fmaf(g, c2, B[s]);
        }
    }
#pragma unroll
    for (int m = 0; m < 4; ++m) {
        M00[m] = fexp2(A[2 * m]) + fexp2(A[2 * m + 1]);
        M01[m] = O[2 * m] + O[2 * m + 1];
        M11[m] = fexp2(B[2 * m]) + fexp2(B[2 * m + 1]);
    }
}

// Single kblock with explicit b2t/b3t arrays (self-transformed step0 path).
__device__ __forceinline__ void kblock_s0(
    float x0, float x1, float p0, float p1,
    const float (&w)[180], const float (&b2t)[10], const float (&b3t)[3],
    float& M00, float& M01, float& M11)
{
    float ra[10], rb[10];
#pragma unroll
    for (int k = 0; k < 10; ++k) {
        float ta = fmaf(p1, w[30 + k],
                   fmaf(p0, w[20 + k],
                   fmaf(x1, w[10 + k],
                   fmaf(x0, w[k], w[40 + k]))));
        float tb = fmaf(x1, w[30 + k],
                   fmaf(x0, w[20 + k],
                   fmaf(p1, w[10 + k],
                   fmaf(p0, w[k], w[40 + k]))));
        ra[k] = fast_rcp(1.0f + fexp2(ta));
        rb[k] = fast_rcp(1.0f + fexp2(tb));
    }
    float ua[10], ub[10];
#pragma unroll
    for (int k = 0; k < 10; ++k) {
        float bb = b2t[k];
        ua[k] = fmaf(ra[0], w[50 + k], bb);
        ub[k] = fmaf(rb[0], w[50 + k], bb);
    }
#pragma unroll
    for (int c = 1; c < 10; ++c) {
#pragma unroll
        for (int k = 0; k < 10; ++k) {
            float ww = w[50 + c * 10 + k];
            ua[k] = fmaf(ra[c], ww, ua[k]);
            ub[k] = fmaf(rb[c], ww, ub[k]);
        }
    }
    float Oa = b3t[0], Ob = b3t[0];
    float T1a = b3t[1], T1b = b3t[1];
    float T2a = b3t[2], T2b = b3t[2];
#pragma unroll
    for (int c = 0; c < 10; ++c) {
        float r2a = fast_rcp(1.0f + fexp2(ua[c]));
        float r2b = fast_rcp(1.0f + fexp2(ub[c]));
        Oa  = fmaf(r2a, w[150 + c], Oa);   Ob  = fmaf(r2b, w[150 + c], Ob);
        T1a = fmaf(r2a, w[160 + c], T1a);  T1b = fmaf(r2b, w[160 + c], T1b);
        T2a = fmaf(r2a, w[170 + c], T2a);  T2b = fmaf(r2b, w[170 + c], T2b);
    }
    M00 = fexp2(T1a) + fexp2(T1b);
    M01 = Oa + Ob;
    M11 = fexp2(T2a) + fexp2(T2b);
}

// ======================================================================
// Shoot-step body with shfl-resident RAW weights (w[180]); b2/b3 via
// uniform pointer (cold). One wave per (batch, a); lane = b.
// ======================================================================
__device__ __forceinline__ void shoot_body(
    int batch, int a, int b,
    float pax, float pay, float qax, float qay,
    float pbx, float pby, float qbx, float qby,
    const float (&w)[180],
    const float* __restrict__ b2, const float* __restrict__ b3,
    float* __restrict__ p_out, float* __restrict__ q_out)
{
    float dhq_x = 0.f, dhq_y = 0.f;
    float g_x = 0.f, g_y = 0.f;
    float cross = fmaf(qax, qby, qay * qbx);

#pragma unroll
    for (int e = 0; e < 2; ++e) {
        float z0 = e ? pbx : pax;
        float z1 = e ? pby : pay;
        float z2 = e ? pax : pbx;
        float z3 = e ? pay : pby;

        float h1[10];
#pragma unroll
        for (int k = 0; k < 10; ++k) {
            float u = fmaf(z3, w[30 + k],
                      fmaf(z2, w[20 + k],
                      fmaf(z1, w[10 + k],
                      fmaf(z0, w[k], w[40 + k]))));
            h1[k] = fast_tanh(u);
        }
        float u2[10];
#pragma unroll
        for (int k = 0; k < 10; ++k) u2[k] = b2[k];
#pragma unroll
        for (int c = 0; c < 10; ++c) {
#pragma unroll
            for (int k = 0; k < 10; ++k) u2[k] = fmaf(h1[c], w[50 + c * 10 + k], u2[k]);
        }
        float h2[10];
        float o0 = b3[0], o1 = b3[1], o2 = b3[2];
#pragma unroll
        for (int c = 0; c < 10; ++c) {
            h2[c] = fast_tanh(u2[c]);
            o0 = fmaf(h2[c], w[150 + c * 3 + 0], o0);
            o1 = fmaf(h2[c], w[150 + c * 3 + 1], o1);
            o2 = fmaf(h2[c], w[150 + c * 3 + 2], o2);
        }
        float e1 = __expf(o1), e2 = __expf(o2);

        dhq_x = fmaf(0.5f, fmaf(e1, qbx, o0 * qby), dhq_x);
        dhq_y = fmaf(0.5f, fmaf(o0, qbx, e2 * qby), dhq_y);

        float d0 = cross;
        float d1 = e1 * qax * qbx;
        float d2 = e2 * qay * qby;

        float du2[10];
#pragma unroll
        for (int c = 0; c < 10; ++c) {
            float dh2 = fmaf(w[150 + c * 3 + 0], d0,
                        fmaf(w[150 + c * 3 + 1], d1, w[150 + c * 3 + 2] * d2));
            du2[c] = dh2 * (1.0f - h2[c] * h2[c]);
        }
        float du1[10];
#pragma unroll
        for (int c = 0; c < 10; ++c) {
            float dh1 = 0.f;
#pragma unroll
            for (int k = 0; k < 10; ++k) dh1 = fmaf(w[50 + c * 10 + k], du2[k], dh1);
            du1[c] = dh1 * (1.0f - h1[c] * h1[c]);
        }
        int c0 = e ? 2 : 0;
        float ga = 0.f, gb = 0.f;
#pragma unroll
        for (int k = 0; k < 10; ++k) {
            ga = fmaf(w[(0 + c0) * 10 + k], du1[k], ga);
            gb = fmaf(w[(1 + c0) * 10 + k], du1[k], gb);
        }
        g_x = fmaf(0.5f, ga, g_x);
        g_y = fmaf(0.5f, gb, g_y);
    }

#pragma unroll
    for (int off = 32; off > 0; off >>= 1) {
        dhq_x += __shfl_xor(dhq_x, off);
        dhq_y += __shfl_xor(dhq_y, off);
        g_x   += __shfl_xor(g_x, off);
        g_y   += __shfl_xor(g_y, off);
    }

    if (b == 0) {
        float* pO = p_out + (batch * NCP + a) * 2;
        float* qO = q_out + (batch * NCP + a) * 2;
        pO[0] = fmaf(DTF, dhq_x, pax);
        pO[1] = fmaf(DTF, dhq_y, pay);
        qO[0] = fmaf(-DTF, g_x, qax);
        qO[1] = fmaf(-DTF, g_y, qay);
    }
}

// ======================================================================
// Launch 1 (fused): blocks 0..1023 = shoot step 0; block 1024 = weight
// transform -> wt (consumed by flow_rest, later launch: race-free);
// blocks 1025.. = flow_step0 (1 wave per template point, SELF-transformed
// weights from raw inputs -> no wt dependency). 64 threads/block.
// ======================================================================
__global__ __launch_bounds__(64, 1)
void shoot0_fused(const float* __restrict__ q0, const float* __restrict__ cp,
                  const float* __restrict__ tpl,
                  const float* __restrict__ W1, const float* __restrict__ b1,
                  const float* __restrict__ W2, const float* __restrict__ b2,
                  const float* __restrict__ W3, const float* __restrict__ b3,
                  float* __restrict__ p_hist, float* __restrict__ q_hist,
                  float* __restrict__ wt, float* __restrict__ out)
{
    int blk = blockIdx.x;
    int lane = threadIdx.x;

    if (blk < BTS * NCP) {
        // ---- shoot step 0 ----
        float w[180];
        load_raw_w(W1, b1, W2, W3, lane, w);
        int batch = blk >> 6;
        int a = blk & (NCP - 1);
        int b = lane;
        float pax = cp[2 * a], pay = cp[2 * a + 1];
        float pbx = cp[2 * b], pby = cp[2 * b + 1];
        float qax = q0[(batch * NCP + a) * 2 + 0], qay = q0[(batch * NCP + a) * 2 + 1];
        float qbx = q0[(batch * NCP + b) * 2 + 0], qby = q0[(batch * NCP + b) * 2 + 1];
        shoot_body(batch, a, b, pax, pay, qax, qay, pbx, pby, qbx, qby,
                   w, b2, b3,
                   p_hist + (size_t)1 * BTS * NCP * 2,
                   q_hist + (size_t)1 * BTS * NCP * 2);
        return;
    }
    if (blk == BTS * NCP) {
        // ---- weight transform for flow_rest ----
        int t = lane;
        if (t < 40) wt[t] = 2.0f * L2E * W1[t];
        if (t < 10) wt[40 + t] = 2.0f * L2E * b1[t];
        for (int i = t; i < 100; i += 64) wt[50 + i] = -4.0f * L2E * W2[i];
        if (t < 10) {
            float s = b2[t];
            for (int c = 0; c < 10; ++c) s += W2[c * 10 + t];
            wt[150 + t] = 2.0f * L2E * s;                 // b2''
            wt[160 + t] = -W3[t * 3 + 0];                 // C0
            wt[170 + t] = -2.0f * L2E * W3[t * 3 + 1];    // C1
            wt[180 + t] = -2.0f * L2E * W3[t * 3 + 2];    // C2
        }
        if (t < 3) {
            float s = b3[t];
            for (int c = 0; c < 10; ++c) s += W3[c * 3 + t];
            wt[190 + t] = (t == 0) ? 0.5f * s : fmaf(L2E, s, -1.0f);
        }
        return;
    }

    // ---- flow step 0: template point i, lane = control point j ----
    int i = blk - (BTS * NCP + 1);
    int j = lane;

    float w[180];
    load_raw_w(W1, b1, W2, W3, j, w);

    // self-transform (raw -> sigmoid-folded), once per block
    float b2t[10], b3t[3];
#pragma unroll
    for (int k = 0; k < 10; ++k) {
        float s = b2[k];
#pragma unroll
        for (int c = 0; c < 10; ++c) s += w[50 + c * 10 + k];
        b2t[k] = 2.0f * L2E * s;
    }
#pragma unroll
    for (int t = 0; t < 3; ++t) {
        float s = b3[t];
#pragma unroll
        for (int c = 0; c < 10; ++c) s += w[150 + c * 3 + t];
        b3t[t] = (t == 0) ? 0.5f * s : fmaf(L2E, s, -1.0f);
    }
#pragma unroll
    for (int t = 0; t < 50; ++t) w[t] *= 2.0f * L2E;
#pragma unroll
    for (int t = 50; t < 150; ++t) w[t] *= -4.0f * L2E;
    {
        float c0a[10], c1a[10], c2a[10];
#pragma unroll
        for (int k = 0; k < 10; ++k) {
            c0a[k] = -w[150 + 3 * k];
            c1a[k] = -2.0f * L2E * w[151 + 3 * k];
            c2a[k] = -2.0f * L2E * w[152 + 3 * k];
        }
#pragma unroll
        for (int k = 0; k < 10; ++k) {
            w[150 + k] = c0a[k];
            w[160 + k] = c1a[k];
            w[170 + k] = c2a[k];
        }
    }

    float x0 = tpl[2 * i], x1 = tpl[2 * i + 1];
    float p0 = cp[2 * j],  p1 = cp[2 * j + 1];

    float M00, M01, M11;
    kblock_s0(x0, x1, p0, p1, w, b2t, b3t, M00, M01, M11);

    const float2* __restrict__ q = (const float2*)q0;
#pragma unroll
    for (int bt = 0; bt < BTS; ++bt) {
        float2 qq = q[bt * NCP + j];
        float vx = fmaf(M00, qq.x, M01 * qq.y);
        float vy = fmaf(M01, qq.x, M11 * qq.y);
#pragma unroll
        for (int off = 32; off > 0; off >>= 1) {
            vx += __shfl_xor(vx, off);
            vy += __shfl_xor(vy, off);
        }
        if (j == 0) {
            out[((size_t)bt * NTPL + i) * 2 + 0] = fmaf(DTF, vx, x0);
            out[((size_t)bt * NTPL + i) * 2 + 1] = fmaf(DTF, vy, x1);
        }
    }
}

// ======================================================================
// Shoot steps 1..5 (multi-launch, R15 structure) with shfl-resident raw
// weights.
// ======================================================================
__global__ __launch_bounds__(64, 1)
void shoot_step(const float* __restrict__ p_in, const float* __restrict__ q_in,
                float* __restrict__ p_out, float* __restrict__ q_out,
                const float* __restrict__ W1, const float* __restrict__ b1,
                const float* __restrict__ W2, const float* __restrict__ b2,
                const float* __restrict__ W3, const float* __restrict__ b3)
{
    int blk = blockIdx.x;
    int batch = blk >> 6;
    int a = blk & (NCP - 1);
    int b = threadIdx.x;

    float w[180];
    load_raw_w(W1, b1, W2, W3, b, w);

    const float* pB = p_in + batch * NCP * 2;
    const float* qB = q_in + batch * NCP * 2;
    float pax = pB[a * 2 + 0], pay = pB[a * 2 + 1];
    float qax = qB[a * 2 + 0], qay = qB[a * 2 + 1];
    float pbx = pB[b * 2 + 0], pby = pB[b * 2 + 1];
    float qbx = qB[b * 2 + 0], qby = qB[b * 2 + 1];

    shoot_body(batch, a, b, pax, pay, qax, qay, pbx, pby, qbx, qby,
               w, b2, b3, p_out, q_out);
}

// ======================================================================
// Flow steps 1..6 (R15-proven, 204 us): wave = (batch, 4 template pts);
// lane = cp j; kblock4 8-stream ILP; transformed weights via wt.
// ======================================================================
__global__ __launch_bounds__(256, 1)
void flow_rest(const float* __restrict__ p_hist, const float* __restrict__ q_hist,
               float* __restrict__ out, const float* __restrict__ wt)
{
    int wid = blockIdx.x * 4 + (threadIdx.x >> 6);
    int j = threadIdx.x & 63;
    int u0 = wid * 4;
    int batch = u0 >> 11;
    int i0 = u0 & (NTPL - 1);

    float w[180];
    load_w(wt, j, w);

    const float2* __restrict__ ph = (const float2*)p_hist;
    const float2* __restrict__ qh = (const float2*)q_hist;

    size_t ob = ((size_t)batch * NTPL + i0) * 2;
    float x0[4], x1[4];
#pragma unroll
    for (int m = 0; m < 4; ++m) {
        x0[m] = out[ob + 2 * m];
        x1[m] = out[ob + 2 * m + 1];
    }

#pragma unroll
    for (int s = 0; s < TSTEPS; ++s) {
        int idx = ((s + 1) * BTS + batch) * NCP + j;
        float2 P = ph[idx];
        float2 Q = qh[idx];
        float M00[4], M01[4], M11[4];
        kblock4(x0, x1, P.x, P.y, w, wt, M00, M01, M11);
        float vx[4], vy[4];
#pragma unroll
        for (int m = 0; m < 4; ++m) {
            vx[m] = fmaf(M00[m], Q.x, M01[m] * Q.y);
            vy[m] = fmaf(M01[m], Q.x, M11[m] * Q.y);
        }
#pragma unroll
        for (int off = 32; off > 0; off >>= 1) {
#pragma unroll
            for (int m = 0; m < 4; ++m) {
                vx[m] += __shfl_xor(vx[m], off);
                vy[m] += __shfl_xor(vy[m], off);
            }
        }
#pragma unroll
        for (int m = 0; m < 4; ++m) {
            x0[m] = fmaf(DTF, vx[m], x0[m]);
            x1[m] = fmaf(DTF, vy[m], x1[m]);
        }
    }

    if (j == 0) {
#pragma unroll
        for (int m = 0; m < 4; ++m) {
            out[ob + 2 * m]     = x0[m];
            out[ob + 2 * m + 1] = x1[m];
        }
    }
}

extern "C" void kernel_launch(void* const* d_in, const int* in_sizes, int n_in,
                              void* d_out, int out_size, void* d_ws, size_t ws_size,
                              hipStream_t stream)
{
    const float* q0  = (const float*)d_in[0];   // [16,64,2]
    const float* tpl = (const float*)d_in[1];   // [2048,2]
    const float* cp  = (const float*)d_in[2];   // [64,2]
    const float* W1  = (const float*)d_in[3];   // [4,10]
    const float* b1  = (const float*)d_in[4];   // [10]
    const float* W2  = (const float*)d_in[5];   // [10,10]
    const float* b2  = (const float*)d_in[6];   // [10]
    const float* W3  = (const float*)d_in[7];   // [10,3]
    const float* b3  = (const float*)d_in[8];   // [3]
    float* out = (float*)d_out;

    float* ws = (float*)d_ws;
    const int slab = BTS * NCP * 2;                      // 2048 floats / slice
    float* p_hist = ws;                                  // 7 slabs (slot 0 unused)
    float* q_hist = ws + (size_t)7 * slab;
    float* wt     = ws + (size_t)14 * slab;              // 193 floats

    // launch 1: shoot s=0 (1024 blks) + wt transform (1 blk) + flow_step0 (2048 blks)
    shoot0_fused<<<BTS * NCP + 1 + NTPL, 64, 0, stream>>>(
        q0, cp, tpl, W1, b1, W2, b2, W3, b3, p_hist, q_hist, wt, out);

    for (int s = 1; s < TSTEPS; ++s) {
        shoot_step<<<BTS * NCP, 64, 0, stream>>>(
            p_hist + (size_t)s * slab, q_hist + (size_t)s * slab,
            p_hist + (size_t)(s + 1) * slab, q_hist + (size_t)(s + 1) * slab,
            W1, b1, W2, b2, W3, b3);
    }

    flow_rest<<<BTS * NTPL / 16, 256, 0, stream>>>(p_hist, q_hist, out, wt);
}

// Round 18
// 273.901 us; speedup vs baseline: 1.8647x; 1.0915x over previous
//
#include <hip/hip_runtime.h>
#include <hip/hip_fp16.h>

#define NCP    64
#define BTS    16
#define NTPL   2048
#define TSTEPS 6
#define DTF    0.2f                      // 1/(T-1)
#define L2E    1.4426950408889634f       // log2(e)

// ---------- fast scalar helpers ----------
__device__ __forceinline__ float fast_rcp(float x) { return __builtin_amdgcn_rcpf(x); }
__device__ __forceinline__ float fexp2(float x)    { return __builtin_amdgcn_exp2f(x); }
__device__ __forceinline__ float fast_tanh(float x) {        // shoot path
    float e = __expf(2.0f * x);
    return 1.0f - 2.0f * fast_rcp(1.0f + e);
}

// ======================================================================
// Raw-weight shfl load (shoot + self-transforming flow_step0):
// w[0..39]=W1 raw, [40..49]=b1, [50..149]=W2 raw, [150..179]=W3 raw.
// ======================================================================
__device__ __forceinline__ void load_raw_w(
    const float* __restrict__ W1, const float* __restrict__ b1,
    const float* __restrict__ W2, const float* __restrict__ W3,
    int lane, float (&w)[180])
{
    float cA = (lane < 40) ? W1[lane] : (lane < 50 ? b1[lane - 40] : 0.f);
    float cB0 = W2[lane];
    float cB1 = (lane < 36) ? W2[64 + lane] : 0.f;
    float cC  = (lane < 30) ? W3[lane] : 0.f;
#pragma unroll
    for (int t = 0; t < 50; ++t)  w[t] = __shfl(cA, t);
#pragma unroll
    for (int t = 0; t < 64; ++t)  w[50 + t] = __shfl(cB0, t);
#pragma unroll
    for (int t = 0; t < 36; ++t)  w[114 + t] = __shfl(cB1, t);
#pragma unroll
    for (int t = 0; t < 30; ++t)  w[150 + t] = __shfl(cC, t);
}

// Transformed weights as BROADCAST half2 (for the fp16 flow_rest path).
// wh layout: [0..39]=W1t [40..49]=b1t [50..149]=W2t [150..159]=C0
//            [160..169]=C1 [170..179]=C2
__device__ __forceinline__ void load_w_h2(const float* __restrict__ wt,
                                          int lane, __half2 (&wh)[180])
{
    float c0 = wt[lane];
    float c1 = wt[64 + lane];
    float c2 = wt[128 + lane];
#pragma unroll
    for (int t = 0; t < 180; ++t) {
        int src = (t < 150) ? t : (t + 10);   // skip b2t at wt[150..159]
        int ch = src >> 6, ix = src & 63;
        float v = (ch == 0) ? c0 : (ch == 1) ? c1 : c2;
        wh[t] = __float2half2_rn(__shfl(v, ix));
    }
}

// ======================================================================
// Quad kernel block, PACKED FP16: the two symmetric eval streams (a,b)
// of each point are the lo/hi halves of __half2 -> v_pk_fma_f16 halves
// the VALU inst count vs the fp32 version. Sigmoid in fp16 (overflow is
// graceful: exp2->inf -> rcp->0, the correct saturation). Epilogue exp2
// and the cross-lane reduction remain fp32.
// ======================================================================
__device__ __forceinline__ void kblock4_h2(
    const float (&x0)[4], const float (&x1)[4], float p0, float p1,
    const __half2 (&wh)[180], const __half2 (&b2h)[10], const __half2 (&b3h)[3],
    float (&M00)[4], float (&M01)[4], float (&M11)[4])
{
    const __half2 one = __float2half2_rn(1.0f);

    __half2 Z0[4], Z1[4], Z2[4], Z3[4];
#pragma unroll
    for (int m = 0; m < 4; ++m) {
        Z0[m] = __floats2half2_rn(x0[m], p0);   // (z0_a, z0_b)
        Z1[m] = __floats2half2_rn(x1[m], p1);
        Z2[m] = __lowhigh2highlow(Z0[m]);       // (p0, x0[m])
        Z3[m] = __lowhigh2highlow(Z1[m]);
    }

    __half2 r[4][10];
#pragma unroll
    for (int k = 0; k < 10; ++k) {
        __half2 w0 = wh[k], w1 = wh[10 + k], w2 = wh[20 + k], w3 = wh[30 + k];
        __half2 bb = wh[40 + k];
#pragma unroll
        for (int m = 0; m < 4; ++m) {
            __half2 t = __hfma2(Z3[m], w3,
                        __hfma2(Z2[m], w2,
                        __hfma2(Z1[m], w1,
                        __hfma2(Z0[m], w0, bb))));
            r[m][k] = h2rcp(__hadd2(one, h2exp2(t)));
        }
    }

    __half2 u[4][10];
#pragma unroll
    for (int k = 0; k < 10; ++k) {
        __half2 ww = wh[50 + k];
        __half2 bb = b2h[k];
#pragma unroll
        for (int m = 0; m < 4; ++m) u[m][k] = __hfma2(r[m][0], ww, bb);
    }
#pragma unroll
    for (int c = 1; c < 10; ++c) {
#pragma unroll
        for (int k = 0; k < 10; ++k) {
            __half2 ww = wh[50 + c * 10 + k];
#pragma unroll
            for (int m = 0; m < 4; ++m) u[m][k] = __hfma2(r[m][c], ww, u[m][k]);
        }
    }

    __half2 O[4], A[4], B[4];
#pragma unroll
    for (int m = 0; m < 4; ++m) { O[m] = b3h[0]; A[m] = b3h[1]; B[m] = b3h[2]; }
#pragma unroll
    for (int c = 0; c < 10; ++c) {
        __half2 c0 = wh[150 + c], c1 = wh[160 + c], c2 = wh[170 + c];
#pragma unroll
        for (int m = 0; m < 4; ++m) {
            __half2 g = h2rcp(__hadd2(one, h2exp2(u[m][c])));
            O[m] = __hfma2(g, c0, O[m]);
            A[m] = __hfma2(g, c1, A[m]);
            B[m] = __hfma2(g, c2, B[m]);
        }
    }
#pragma unroll
    for (int m = 0; m < 4; ++m) {
        M00[m] = fexp2(__low2float(A[m])) + fexp2(__high2float(A[m]));
        M01[m] = __low2float(O[m]) + __high2float(O[m]);
        M11[m] = fexp2(__low2float(B[m])) + fexp2(__high2float(B[m]));
    }
}

// Single fp32 kblock with explicit b2t/b3t arrays (flow_step0 path).
__device__ __forceinline__ void kblock_s0(
    float x0, float x1, float p0, float p1,
    const float (&w)[180], const float (&b2t)[10], const float (&b3t)[3],
    float& M00, float& M01, float& M11)
{
    float ra[10], rb[10];
#pragma unroll
    for (int k = 0; k < 10; ++k) {
        float ta = fmaf(p1, w[30 + k],
                   fmaf(p0, w[20 + k],
                   fmaf(x1, w[10 + k],
                   fmaf(x0, w[k], w[40 + k]))));
        float tb = fmaf(x1, w[30 + k],
                   fmaf(x0, w[20 + k],
                   fmaf(p1, w[10 + k],
                   fmaf(p0, w[k], w[40 + k]))));
        ra[k] = fast_rcp(1.0f + fexp2(ta));
        rb[k] = fast_rcp(1.0f + fexp2(tb));
    }
    float ua[10], ub[10];
#pragma unroll
    for (int k = 0; k < 10; ++k) {
        float bb = b2t[k];
        ua[k] = fmaf(ra[0], w[50 + k], bb);
        ub[k] = fmaf(rb[0], w[50 + k], bb);
    }
#pragma unroll
    for (int c = 1; c < 10; ++c) {
#pragma unroll
        for (int k = 0; k < 10; ++k) {
            float ww = w[50 + c * 10 + k];
            ua[k] = fmaf(ra[c], ww, ua[k]);
            ub[k] = fmaf(rb[c], ww, ub[k]);
        }
    }
    float Oa = b3t[0], Ob = b3t[0];
    float T1a = b3t[1], T1b = b3t[1];
    float T2a = b3t[2], T2b = b3t[2];
#pragma unroll
    for (int c = 0; c < 10; ++c) {
        float r2a = fast_rcp(1.0f + fexp2(ua[c]));
        float r2b = fast_rcp(1.0f + fexp2(ub[c]));
        Oa  = fmaf(r2a, w[150 + c], Oa);   Ob  = fmaf(r2b, w[150 + c], Ob);
        T1a = fmaf(r2a, w[160 + c], T1a);  T1b = fmaf(r2b, w[160 + c], T1b);
        T2a = fmaf(r2a, w[170 + c], T2a);  T2b = fmaf(r2b, w[170 + c], T2b);
    }
    M00 = fexp2(T1a) + fexp2(T1b);
    M01 = Oa + Ob;
    M11 = fexp2(T2a) + fexp2(T2b);
}

// ======================================================================
// Shoot-step body (fp32, proven): shfl-resident RAW weights.
// ======================================================================
__device__ __forceinline__ void shoot_body(
    int batch, int a, int b,
    float pax, float pay, float qax, float qay,
    float pbx, float pby, float qbx, float qby,
    const float (&w)[180],
    const float* __restrict__ b2, const float* __restrict__ b3,
    float* __restrict__ p_out, float* __restrict__ q_out)
{
    float dhq_x = 0.f, dhq_y = 0.f;
    float g_x = 0.f, g_y = 0.f;
    float cross = fmaf(qax, qby, qay * qbx);

#pragma unroll
    for (int e = 0; e < 2; ++e) {
        float z0 = e ? pbx : pax;
        float z1 = e ? pby : pay;
        float z2 = e ? pax : pbx;
        float z3 = e ? pay : pby;

        float h1[10];
#pragma unroll
        for (int k = 0; k < 10; ++k) {
            float u = fmaf(z3, w[30 + k],
                      fmaf(z2, w[20 + k],
                      fmaf(z1, w[10 + k],
                      fmaf(z0, w[k], w[40 + k]))));
            h1[k] = fast_tanh(u);
        }
        float u2[10];
#pragma unroll
        for (int k = 0; k < 10; ++k) u2[k] = b2[k];
#pragma unroll
        for (int c = 0; c < 10; ++c) {
#pragma unroll
            for (int k = 0; k < 10; ++k) u2[k] = fmaf(h1[c], w[50 + c * 10 + k], u2[k]);
        }
        float h2[10];
        float o0 = b3[0], o1 = b3[1], o2 = b3[2];
#pragma unroll
        for (int c = 0; c < 10; ++c) {
            h2[c] = fast_tanh(u2[c]);
            o0 = fmaf(h2[c], w[150 + c * 3 + 0], o0);
            o1 = fmaf(h2[c], w[150 + c * 3 + 1], o1);
            o2 = fmaf(h2[c], w[150 + c * 3 + 2], o2);
        }
        float e1 = __expf(o1), e2 = __expf(o2);

        dhq_x = fmaf(0.5f, fmaf(e1, qbx, o0 * qby), dhq_x);
        dhq_y = fmaf(0.5f, fmaf(o0, qbx, e2 * qby), dhq_y);

        float d0 = cross;
        float d1 = e1 * qax * qbx;
        float d2 = e2 * qay * qby;

        float du2[10];
#pragma unroll
        for (int c = 0; c < 10; ++c) {
            float dh2 = fmaf(w[150 + c * 3 + 0], d0,
                        fmaf(w[150 + c * 3 + 1], d1, w[150 + c * 3 + 2] * d2));
            du2[c] = dh2 * (1.0f - h2[c] * h2[c]);
        }
        float du1[10];
#pragma unroll
        for (int c = 0; c < 10; ++c) {
            float dh1 = 0.f;
#pragma unroll
            for (int k = 0; k < 10; ++k) dh1 = fmaf(w[50 + c * 10 + k], du2[k], dh1);
            du1[c] = dh1 * (1.0f - h1[c] * h1[c]);
        }
        int c0 = e ? 2 : 0;
        float ga = 0.f, gb = 0.f;
#pragma unroll
        for (int k = 0; k < 10; ++k) {
            ga = fmaf(w[(0 + c0) * 10 + k], du1[k], ga);
            gb = fmaf(w[(1 + c0) * 10 + k], du1[k], gb);
        }
        g_x = fmaf(0.5f, ga, g_x);
        g_y = fmaf(0.5f, gb, g_y);
    }

#pragma unroll
    for (int off = 32; off > 0; off >>= 1) {
        dhq_x += __shfl_xor(dhq_x, off);
        dhq_y += __shfl_xor(dhq_y, off);
        g_x   += __shfl_xor(g_x, off);
        g_y   += __shfl_xor(g_y, off);
    }

    if (b == 0) {
        float* pO = p_out + (batch * NCP + a) * 2;
        float* qO = q_out + (batch * NCP + a) * 2;
        pO[0] = fmaf(DTF, dhq_x, pax);
        pO[1] = fmaf(DTF, dhq_y, pay);
        qO[0] = fmaf(-DTF, g_x, qax);
        qO[1] = fmaf(-DTF, g_y, qay);
    }
}

// ======================================================================
// Launch 1 (fused): blocks 0..1023 = shoot step 0; block 1024 = weight
// transform -> wt; blocks 1025.. = flow_step0 (self-transformed).
// ======================================================================
__global__ __launch_bounds__(64, 1)
void shoot0_fused(const float* __restrict__ q0, const float* __restrict__ cp,
                  const float* __restrict__ tpl,
                  const float* __restrict__ W1, const float* __restrict__ b1,
                  const float* __restrict__ W2, const float* __restrict__ b2,
                  const float* __restrict__ W3, const float* __restrict__ b3,
                  float* __restrict__ p_hist, float* __restrict__ q_hist,
                  float* __restrict__ wt, float* __restrict__ out)
{
    int blk = blockIdx.x;
    int lane = threadIdx.x;

    if (blk < BTS * NCP) {
        float w[180];
        load_raw_w(W1, b1, W2, W3, lane, w);
        int batch = blk >> 6;
        int a = blk & (NCP - 1);
        int b = lane;
        float pax = cp[2 * a], pay = cp[2 * a + 1];
        float pbx = cp[2 * b], pby = cp[2 * b + 1];
        float qax = q0[(batch * NCP + a) * 2 + 0], qay = q0[(batch * NCP + a) * 2 + 1];
        float qbx = q0[(batch * NCP + b) * 2 + 0], qby = q0[(batch * NCP + b) * 2 + 1];
        shoot_body(batch, a, b, pax, pay, qax, qay, pbx, pby, qbx, qby,
                   w, b2, b3,
                   p_hist + (size_t)1 * BTS * NCP * 2,
                   q_hist + (size_t)1 * BTS * NCP * 2);
        return;
    }
    if (blk == BTS * NCP) {
        int t = lane;
        if (t < 40) wt[t] = 2.0f * L2E * W1[t];
        if (t < 10) wt[40 + t] = 2.0f * L2E * b1[t];
        for (int i = t; i < 100; i += 64) wt[50 + i] = -4.0f * L2E * W2[i];
        if (t < 10) {
            float s = b2[t];
            for (int c = 0; c < 10; ++c) s += W2[c * 10 + t];
            wt[150 + t] = 2.0f * L2E * s;                 // b2''
            wt[160 + t] = -W3[t * 3 + 0];                 // C0
            wt[170 + t] = -2.0f * L2E * W3[t * 3 + 1];    // C1
            wt[180 + t] = -2.0f * L2E * W3[t * 3 + 2];    // C2
        }
        if (t < 3) {
            float s = b3[t];
            for (int c = 0; c < 10; ++c) s += W3[c * 3 + t];
            wt[190 + t] = (t == 0) ? 0.5f * s : fmaf(L2E, s, -1.0f);
        }
        return;
    }

    // ---- flow step 0 ----
    int i = blk - (BTS * NCP + 1);
    int j = lane;

    float w[180];
    load_raw_w(W1, b1, W2, W3, j, w);

    float b2t[10], b3t[3];
#pragma unroll
    for (int k = 0; k < 10; ++k) {
        float s = b2[k];
#pragma unroll
        for (int c = 0; c < 10; ++c) s += w[50 + c * 10 + k];
        b2t[k] = 2.0f * L2E * s;
    }
#pragma unroll
    for (int t = 0; t < 3; ++t) {
        float s = b3[t];
#pragma unroll
        for (int c = 0; c < 10; ++c) s += w[150 + c * 3 + t];
        b3t[t] = (t == 0) ? 0.5f * s : fmaf(L2E, s, -1.0f);
    }
#pragma unroll
    for (int t = 0; t < 50; ++t) w[t] *= 2.0f * L2E;
#pragma unroll
    for (int t = 50; t < 150; ++t) w[t] *= -4.0f * L2E;
    {
        float c0a[10], c1a[10], c2a[10];
#pragma unroll
        for (int k = 0; k < 10; ++k) {
            c0a[k] = -w[150 + 3 * k];
            c1a[k] = -2.0f * L2E * w[151 + 3 * k];
            c2a[k] = -2.0f * L2E * w[152 + 3 * k];
        }
#pragma unroll
        for (int k = 0; k < 10; ++k) {
            w[150 + k] = c0a[k];
            w[160 + k] = c1a[k];
            w[170 + k] = c2a[k];
        }
    }

    float x0 = tpl[2 * i], x1 = tpl[2 * i + 1];
    float p0 = cp[2 * j],  p1 = cp[2 * j + 1];

    float M00, M01, M11;
    kblock_s0(x0, x1, p0, p1, w, b2t, b3t, M00, M01, M11);

    const float2* __restrict__ q = (const float2*)q0;
#pragma unroll
    for (int bt = 0; bt < BTS; ++bt) {
        float2 qq = q[bt * NCP + j];
        float vx = fmaf(M00, qq.x, M01 * qq.y);
        float vy = fmaf(M01, qq.x, M11 * qq.y);
#pragma unroll
        for (int off = 32; off > 0; off >>= 1) {
            vx += __shfl_xor(vx, off);
            vy += __shfl_xor(vy, off);
        }
        if (j == 0) {
            out[((size_t)bt * NTPL + i) * 2 + 0] = fmaf(DTF, vx, x0);
            out[((size_t)bt * NTPL + i) * 2 + 1] = fmaf(DTF, vy, x1);
        }
    }
}

// ======================================================================
// Shoot steps 1..5 (multi-launch, shfl-resident raw weights).
// ======================================================================
__global__ __launch_bounds__(64, 1)
void shoot_step(const float* __restrict__ p_in, const float* __restrict__ q_in,
                float* __restrict__ p_out, float* __restrict__ q_out,
                const float* __restrict__ W1, const float* __restrict__ b1,
                const float* __restrict__ W2, const float* __restrict__ b2,
                const float* __restrict__ W3, const float* __restrict__ b3)
{
    int blk = blockIdx.x;
    int batch = blk >> 6;
    int a = blk & (NCP - 1);
    int b = threadIdx.x;

    float w[180];
    load_raw_w(W1, b1, W2, W3, b, w);

    const float* pB = p_in + batch * NCP * 2;
    const float* qB = q_in + batch * NCP * 2;
    float pax = pB[a * 2 + 0], pay = pB[a * 2 + 1];
    float qax = qB[a * 2 + 0], qay = qB[a * 2 + 1];
    float pbx = pB[b * 2 + 0], pby = pB[b * 2 + 1];
    float qbx = qB[b * 2 + 0], qby = qB[b * 2 + 1];

    shoot_body(batch, a, b, pax, pay, qax, qay, pbx, pby, qbx, qby,
               w, b2, b3, p_out, q_out);
}

// ======================================================================
// Flow steps 1..6: wave = (batch, 4 template pts); lane = cp j.
// PACKED FP16 kblock4 (v_pk_fma_f16 halves the inst count).
// ======================================================================
__global__ __launch_bounds__(256, 1)
void flow_rest(const float* __restrict__ p_hist, const float* __restrict__ q_hist,
               float* __restrict__ out, const float* __restrict__ wt)
{
    int wid = blockIdx.x * 4 + (threadIdx.x >> 6);
    int j = threadIdx.x & 63;
    int u0 = wid * 4;
    int batch = u0 >> 11;
    int i0 = u0 & (NTPL - 1);

    __half2 wh[180];
    load_w_h2(wt, j, wh);
    __half2 b2h[10], b3h[3];
#pragma unroll
    for (int k = 0; k < 10; ++k) b2h[k] = __float2half2_rn(wt[150 + k]);
#pragma unroll
    for (int t = 0; t < 3; ++t)  b3h[t] = __float2half2_rn(wt[190 + t]);

    const float2* __restrict__ ph = (const float2*)p_hist;
    const float2* __restrict__ qh = (const float2*)q_hist;

    size_t ob = ((size_t)batch * NTPL + i0) * 2;
    float x0[4], x1[4];
#pragma unroll
    for (int m = 0; m < 4; ++m) {
        x0[m] = out[ob + 2 * m];
        x1[m] = out[ob + 2 * m + 1];
    }

#pragma unroll
    for (int s = 0; s < TSTEPS; ++s) {
        int idx = ((s + 1) * BTS + batch) * NCP + j;
        float2 P = ph[idx];
        float2 Q = qh[idx];
        float M00[4], M01[4], M11[4];
        kblock4_h2(x0, x1, P.x, P.y, wh, b2h, b3h, M00, M01, M11);
        float vx[4], vy[4];
#pragma unroll
        for (int m = 0; m < 4; ++m) {
            vx[m] = fmaf(M00[m], Q.x, M01[m] * Q.y);
            vy[m] = fmaf(M01[m], Q.x, M11[m] * Q.y);
        }
#pragma unroll
        for (int off = 32; off > 0; off >>= 1) {
#pragma unroll
            for (int m = 0; m < 4; ++m) {
                vx[m] += __shfl_xor(vx[m], off);
                vy[m] += __shfl_xor(vy[m], off);
            }
        }
#pragma unroll
        for (int m = 0; m < 4; ++m) {
            x0[m] = fmaf(DTF, vx[m], x0[m]);
            x1[m] = fmaf(DTF, vy[m], x1[m]);
        }
    }

    if (j == 0) {
#pragma unroll
        for (int m = 0; m < 4; ++m) {
            out[ob + 2 * m]     = x0[m];
            out[ob + 2 * m + 1] = x1[m];
        }
    }
}

extern "C" void kernel_launch(void* const* d_in, const int* in_sizes, int n_in,
                              void* d_out, int out_size, void* d_ws, size_t ws_size,
                              hipStream_t stream)
{
    const float* q0  = (const float*)d_in[0];   // [16,64,2]
    const float* tpl = (const float*)d_in[1];   // [2048,2]
    const float* cp  = (const float*)d_in[2];   // [64,2]
    const float* W1  = (const float*)d_in[3];   // [4,10]
    const float* b1  = (const float*)d_in[4];   // [10]
    const float* W2  = (const float*)d_in[5];   // [10,10]
    const float* b2  = (const float*)d_in[6];   // [10]
    const float* W3  = (const float*)d_in[7];   // [10,3]
    const float* b3  = (const float*)d_in[8];   // [3]
    float* out = (float*)d_out;

    float* ws = (float*)d_ws;
    const int slab = BTS * NCP * 2;                      // 2048 floats / slice
    float* p_hist = ws;                                  // 7 slabs (slot 0 unused)
    float* q_hist = ws + (size_t)7 * slab;
    float* wt     = ws + (size_t)14 * slab;              // 193 floats

    shoot0_fused<<<BTS * NCP + 1 + NTPL, 64, 0, stream>>>(
        q0, cp, tpl, W1, b1, W2, b2, W3, b3, p_hist, q_hist, wt, out);

    for (int s = 1; s < TSTEPS; ++s) {
        shoot_step<<<BTS * NCP, 64, 0, stream>>>(
            p_hist + (size_t)s * slab, q_hist + (size_t)s * slab,
            p_hist + (size_t)(s + 1) * slab, q_hist + (size_t)(s + 1) * slab,
            W1, b1, W2, b2, W3, b3);
    }

    flow_rest<<<BTS * NTPL / 16, 256, 0, stream>>>(p_hist, q_hist, out, wt);
}